// Round 3
// baseline (2130.176 us; speedup 1.0000x reference)
//
#include <hip/hip_runtime.h>

// ECGLSTM: B=256, T=5000, input_size=1, H=64, fused FC(64->128)+ReLU.
// R8: kill the LDS h-broadcast (the real R5/R7 bottleneck: 4 waves x 16
// ds_read_b128 x ~12cy = ~770cy/step on the ONE shared LDS pipe).
//   - R5 layout: tid = gate row (wave w = gate type w, lane = hidden unit).
//   - c/h update REPLICATED in all 4 waves (each wave reads all 4 gate
//     activations itself) -> h[lane] lives in a register `hv`, identical
//     in every wave.
//   - h broadcast for the dot via v_readlane (VALU, per-SIMD, parallel
//     across waves) feeding v_fmac_f32 with an SGPR operand -> ZERO LDS
//     traffic for h.
//   - LDS per step: 256-float gate exchange only (conflict-free b32 write
//     + 4 conflict-free b32 reads per lane) + ONE barrier. Double-buffered
//     gbuf makes one barrier sufficient (step t+2's write to gbuf[P]
//     happens after t+1's barrier, which is after every wave's step-t
//     reads of gbuf[P]).
//   - Activation formulas identical to R7 (branchless per-wave constants;
//     fmaf(1,x,0)==x exactly for sigmoid lanes).

#define LSTM_H 64
#define LSTM_T 5000
#define LSTM_B 256

__device__ __forceinline__ float fast_rcp(float v) {
    return __builtin_amdgcn_rcpf(v);
}

// Wave-uniform broadcast of lane k's value (v_readlane_b32 -> SGPR).
__device__ __forceinline__ float lane_bcast(float v, int k) {
    return __builtin_bit_cast(float,
        __builtin_amdgcn_readlane(__builtin_bit_cast(int, v), k));
}

__global__ __launch_bounds__(256) void ECGLSTM_lstm_rl(
    const float* __restrict__ x,      // [B, T]
    const float* __restrict__ W_ih,   // [4H, 1]
    const float* __restrict__ W_hh,   // [4H, H]
    const float* __restrict__ b_ih,   // [4H]
    const float* __restrict__ b_hh,   // [4H]
    const float* __restrict__ W_fc,   // [128, H]
    const float* __restrict__ b_fc,   // [128]
    float* __restrict__ out)          // [B, 128]
{
    const int tid  = threadIdx.x;     // gate row 0..255
    const int lane = tid & 63;        // hidden unit
    const int w    = tid >> 6;        // gate type: 0=i 1=f 2=g 3=o
    const int b    = blockIdx.x;

    __shared__ float xch[LSTM_T];             // whole x row, staged once
    __shared__ float gbuf[2][4][LSTM_H];      // double-buffered gate acts
    __shared__ float hfin[LSTM_H];            // final h for the FC

    // Stage x (coalesced, once)
    const float* xb = x + b * LSTM_T;
    for (int i = tid; i < LSTM_T; i += 256) xch[i] = xb[i];

    // W_hh row `tid` -> 64 scalar VGPRs (static indices only)
    float wreg[LSTM_H];
    {
        const float4* wrow = reinterpret_cast<const float4*>(W_hh + tid * LSTM_H);
        #pragma unroll
        for (int i = 0; i < LSTM_H / 4; ++i) {
            float4 v = wrow[i];
            wreg[4 * i]     = v.x;
            wreg[4 * i + 1] = v.y;
            wreg[4 * i + 2] = v.z;
            wreg[4 * i + 3] = v.w;
        }
    }
    const float wih  = W_ih[tid];
    const float bias = b_ih[tid] + b_hh[tid];
    const bool  is_t = (w == 2);                  // tanh gate (wave-uniform)
    const float aexp = is_t ? -2.0f : -1.0f;      // e = exp(aexp * gate)
    const float smul = is_t ?  2.0f :  1.0f;      // act = s*rcp(1+e) + d
    const float dadd = is_t ? -1.0f :  0.0f;

    float hv = 0.0f;                  // h[lane], replicated in all 4 waves
    float c  = 0.0f;                  // c[lane], replicated in all 4 waves
    __syncthreads();                  // x staged

    // One step: dot from registers (readlane broadcast), gate exchange via
    // gbuf[P], ONE barrier, replicated c/h update.
    #define LSTM_STEP(t, P)                                                    \
    {                                                                          \
        const float xv = xch[(t)];                      /* broadcast b32 */    \
        float a0 = 0.f, a1 = 0.f, a2 = 0.f, a3 = 0.f;                          \
        _Pragma("unroll")                                                      \
        for (int j = 0; j < 16; ++j) {                                         \
            a0 = fmaf(lane_bcast(hv, j),      wreg[j],      a0);               \
            a1 = fmaf(lane_bcast(hv, j + 16), wreg[j + 16], a1);               \
            a2 = fmaf(lane_bcast(hv, j + 32), wreg[j + 32], a2);               \
            a3 = fmaf(lane_bcast(hv, j + 48), wreg[j + 48], a3);               \
        }                                                                      \
        float dot = (a0 + a1) + (a2 + a3);                                     \
        float gv  = fmaf(xv, wih, bias) + dot;                                 \
        float e   = __expf(aexp * gv);                                         \
        float act = fmaf(smul, fast_rcp(1.0f + e), dadd);                      \
        gbuf[(P)][w][lane] = act;                       /* conflict-free */    \
        __syncthreads();                                /* the ONE barrier */  \
        const float ig = gbuf[(P)][0][lane];                                   \
        const float fg = gbuf[(P)][1][lane];                                   \
        const float gg = gbuf[(P)][2][lane];                                   \
        const float og = gbuf[(P)][3][lane];                                   \
        c = fmaf(fg, c, ig * gg);                                              \
        float e2 = __expf(2.0f * c);                                           \
        float th = 1.0f - 2.0f * fast_rcp(e2 + 1.0f);                          \
        hv = og * th;                                   /* same in all waves*/ \
    }

    for (int t = 0; t < LSTM_T; t += 2) {
        LSTM_STEP(t, 0);
        LSTM_STEP(t + 1, 1);
    }
    #undef LSTM_STEP

    // Publish final h (wave 0 has it; all waves identical), then FC+ReLU.
    if (tid < LSTM_H) hfin[tid] = hv;
    __syncthreads();
    if (tid < 128) {
        float s = b_fc[tid];
        const float4* wf = reinterpret_cast<const float4*>(W_fc + tid * LSTM_H);
        const float4* h4 = reinterpret_cast<const float4*>(hfin);
        #pragma unroll
        for (int i = 0; i < LSTM_H / 4; ++i) {
            float4 wv = wf[i];
            float4 hvv = h4[i];
            s = fmaf(hvv.x, wv.x, s);
            s = fmaf(hvv.y, wv.y, s);
            s = fmaf(hvv.z, wv.z, s);
            s = fmaf(hvv.w, wv.w, s);
        }
        out[b * 128 + tid] = fmaxf(s, 0.0f);
    }
}

extern "C" void kernel_launch(void* const* d_in, const int* in_sizes, int n_in,
                              void* d_out, int out_size, void* d_ws, size_t ws_size,
                              hipStream_t stream) {
    const float* x    = (const float*)d_in[0];
    const float* W_ih = (const float*)d_in[1];
    const float* W_hh = (const float*)d_in[2];
    const float* b_ih = (const float*)d_in[3];
    const float* b_hh = (const float*)d_in[4];
    const float* W_fc = (const float*)d_in[5];
    const float* b_fc = (const float*)d_in[6];
    float* out = (float*)d_out;

    ECGLSTM_lstm_rl<<<LSTM_B, 256, 0, stream>>>(
        x, W_ih, W_hh, b_ih, b_hh, W_fc, b_fc, out);
}